// Round 11
// baseline (141.376 us; speedup 1.0000x reference)
//
#include <hip/hip_runtime.h>
#include <hip/hip_cooperative_groups.h>
#include <hip/hip_bf16.h>
#include <math.h>

namespace cg = cooperative_groups;

#define BS 4096
#define DD 512
#define NCLS 100
#define NROWS 8192
#define NSLAB 256            // 256 slabs x 32 cols
#define INV_T (1.0f / 0.07f)
#define NEG_BIG (-3.0e38f)

typedef __attribute__((ext_vector_type(8))) short short8;      // 8 bf16 (4 VGPR)
typedef __attribute__((ext_vector_type(8))) unsigned short ushort8;
typedef __attribute__((ext_vector_type(4))) float f32x4;

__device__ __forceinline__ unsigned short f2bf(float x) {
    __hip_bfloat16 h = __float2bfloat16(x);
    return *reinterpret_cast<unsigned short*>(&h);
}

// ---- phase 0: protos fp32 -> bf16 (112 rows, zero-padded), part = 0..13 ----
__device__ __forceinline__ void conv_protos(int part, int tid,
                                            const float* __restrict__ protos,
                                            unsigned short* __restrict__ pB) {
    const int t = part * 512 + tid;          // 0..7167 ushort8-chunks (112*512/8)
    const int r = t >> 6;
    const int kk = (t & 63) << 3;
    float4 f0 = {0,0,0,0}, f1 = {0,0,0,0};
    if (r < NCLS) {
        const float4* s = (const float4*)(protos + (size_t)r * DD + kk);
        f0 = s[0]; f1 = s[1];
    }
    ushort8 o;
    o[0]=f2bf(f0.x); o[1]=f2bf(f0.y); o[2]=f2bf(f0.z); o[3]=f2bf(f0.w);
    o[4]=f2bf(f1.x); o[5]=f2bf(f1.y); o[6]=f2bf(f1.z); o[7]=f2bf(f1.w);
    *reinterpret_cast<ushort8*>(pB + (size_t)r * DD + kk) = o;
}

// ---- phase 1a: stage 32-row feature slab -> swizzled bf16 LDS ----
__device__ __forceinline__ void gemm_stage(char* lds, int nt, int tid,
                                           const float* __restrict__ feats) {
    const int v  = nt >> 7;
    const int b0 = (nt & 127) * 32;
    float4 fr[8];
#pragma unroll
    for (int it = 0; it < 8; ++it) {         // issue all 8 loads: one HBM latency
        const int i = tid + it * 512;
        const int r = i >> 7, c4 = i & 127;
        fr[it] = *(const float4*)(feats + (size_t)((b0 + r) * 2 + v) * DD + c4 * 4);
    }
#pragma unroll
    for (int it = 0; it < 8; ++it) {
        const int i = tid + it * 512;
        const int r = i >> 7, c4 = i & 127;
        ushort4 o = { f2bf(fr[it].x), f2bf(fr[it].y), f2bf(fr[it].z), f2bf(fr[it].w) };
        const int byte = (r * 1024 + c4 * 8) ^ ((r & 7) << 4);
        *reinterpret_cast<ushort4*>(&lds[byte]) = o;
    }
}

// ---- phase 1b: MFMA GEMM (128x32 per block) + in-register stats + stash ----
__device__ __forceinline__ void gemm_main(char* lds, int nt, int tid,
                                          const unsigned short* __restrict__ pB,
                                          const int* __restrict__ labels,
                                          float4* __restrict__ PA,
                                          float4* __restrict__ PBd,
                                          float* __restrict__ stash) {
    __syncthreads();                          // LDS stage visible (fused: after grid sync, harmless)
    const int w = tid >> 6, lane = tid & 63;
    const int m = lane & 15, kb = lane >> 4;
    const int arow = min(w * 16 + m, NCLS - 1);           // clamp; rows >=100 never published
    const short8* apv = (const short8*)((const short*)pB + (size_t)arow * DD + kb * 8);

    const int swz   = (m & 7) << 4;
    const int base0 = m * 1024 + kb * 16;
    const int base1 = (m + 16) * 1024 + kb * 16;
    f32x4 acc0 = {}, acc1 = {};
#pragma unroll
    for (int k = 0; k < 16; ++k) {            // K = 512 = 16 x 32; A: one 16B L2 load
        const short8 a   = apv[k * 4];
        const short8 bf0 = *reinterpret_cast<const short8*>(&lds[(base0 + k * 64) ^ swz]);
        const short8 bf1 = *reinterpret_cast<const short8*>(&lds[(base1 + k * 64) ^ swz]);
        acc0 = __builtin_amdgcn_mfma_f32_16x16x32_bf16(a, bf0, acc0, 0, 0, 0);
        acc1 = __builtin_amdgcn_mfma_f32_16x16x32_bf16(a, bf1, acc1, 0, 0, 0);
    }
#pragma unroll
    for (int r = 0; r < 4; ++r) { acc0[r] *= INV_T; acc1[r] *= INV_T; }

    // C/D layout: col = lane&15 (+16 for acc1), row = w*16 + kb*4 + r
    const int j0 = nt * 32 + m, j1 = j0 + 16;
    const int lb0 = labels[j0 & (BS - 1)], lb1 = labels[j1 & (BS - 1)];

    // stash: column j's matched logit is S[label[j]][j] — exactly one lane holds it (lb<100 -> w<=6)
    if ((lb0 >> 4) == w && ((lb0 >> 2) & 3) == kb) {
        const int rr = lb0 & 3;
        stash[j0] = (rr==0)?acc0[0]:(rr==1)?acc0[1]:(rr==2)?acc0[2]:acc0[3];
    }
    if ((lb1 >> 4) == w && ((lb1 >> 2) & 3) == kb) {
        const int rr = lb1 & 3;
        stash[j1] = (rr==0)?acc1[0]:(rr==1)?acc1[1]:(rr==2)?acc1[2]:acc1[3];
    }

    // per-class-row stats over this slab's 32 columns: 16-lane shfl butterflies
#pragma unroll
    for (int r = 0; r < 4; ++r) {
        const int row = w * 16 + kb * 4 + r;
        const float x0 = acc0[r], x1 = acc1[r];
        float m1, m2; int i1;
        if (x0 >= x1) { m1 = x0; m2 = x1; i1 = j0; } else { m1 = x1; m2 = x0; i1 = j1; }
#pragma unroll
        for (int s = 1; s < 16; s <<= 1) {    // disjoint-union butterfly: exact top-2
            const float om1 = __shfl_xor(m1, s);
            const float om2 = __shfl_xor(m2, s);
            const int   oi1 = __shfl_xor(i1, s);
            if (om1 > m1) { m2 = fmaxf(m1, om2); m1 = om1; i1 = oi1; }
            else          { m2 = fmaxf(m2, om1); }
        }
        float ea = __expf(x0 - m1) + __expf(x1 - m1);
        float ee = (j0 != i1 ? __expf(x0 - m2) : 0.f) + (j1 != i1 ? __expf(x1 - m2) : 0.f);
        float pp = 0.f, nn = 0.f;
        if (lb0 == row) { pp += x0 - m1; nn += 1.f; }
        if (lb1 == row) { pp += x1 - m1; nn += 1.f; }
#pragma unroll
        for (int s = 1; s < 16; s <<= 1) {
            ea += __shfl_xor(ea, s);
            ee += __shfl_xor(ee, s);
            pp += __shfl_xor(pp, s);
            nn += __shfl_xor(nn, s);
        }
        if (m == 0 && row < NCLS) {           // plain stores; visible after next grid sync
            PA[row * NSLAB + nt]  = make_float4(m1, m2, ea, ee);
            PBd[row * NSLAB + nt] = make_float4(pp, nn, (float)i1, 0.f);
        }
    }
}

// ---- phase 2: per-class merge of 256 slab partials + loss (512 threads) ----
__device__ __forceinline__ void merge_class(char* ldsraw, int c, int tid,
                                            const float4* __restrict__ PA,
                                            const float4* __restrict__ PBd,
                                            const float* __restrict__ stash,
                                            const int* __restrict__ labels,
                                            float* __restrict__ out) {
    float* s1 = (float*)ldsraw;
    float* s2 = s1 + 512;
    int*   si = (int*)(s2 + 512);
    float* r1 = (float*)(si + 512);
    float* r2 = r1 + 512;
    float* r3 = r2 + 512;

    float m1, m2, ea, ee, pp, nn; int i1;
    if (tid < NSLAB) {
        const float4 A  = PA[c * NSLAB + tid];
        const float4 Bq = PBd[c * NSLAB + tid];
        m1 = A.x; m2 = A.y; ea = A.z; ee = A.w;
        pp = Bq.x; nn = Bq.y; i1 = (int)Bq.z;
    } else {                                  // neutral: contributes exact 0 everywhere
        m1 = NEG_BIG; m2 = NEG_BIG; ea = 0.f; ee = 0.f; pp = 0.f; nn = 0.f; i1 = -1;
    }
    s1[tid] = m1; s2[tid] = m2; si[tid] = i1;
    __syncthreads();
    for (int s = 256; s > 0; s >>= 1) {
        if (tid < s) {
            const float b1 = s1[tid + s], b2 = s2[tid + s];
            if (b1 > s1[tid]) { s2[tid] = fmaxf(s1[tid], b2); s1[tid] = b1; si[tid] = si[tid + s]; }
            else              { s2[tid] = fmaxf(s2[tid], b1); }
        }
        __syncthreads();
    }
    const float gm1 = s1[0], gm2 = s2[0];
    const int   gi1 = si[0];
    __syncthreads();

    // rescaled contributions (all exponents <= 0; neutral rows give exact 0)
    const float e1c = ea * __expf(m1 - gm1);
    const float e2c = (tid < NSLAB && (gi1 >> 5) == tid) ? ee * __expf(m2 - gm2)
                                                         : ea * __expf(m1 - gm2);
    const float pc  = pp + nn * (m1 - gm1);
    r1[tid] = e1c; r2[tid] = e2c; r3[tid] = pc;
    __syncthreads();
    for (int s = 256; s > 0; s >>= 1) {
        if (tid < s) { r1[tid] += r1[tid + s]; r2[tid] += r2[tid + s]; r3[tid] += r3[tid + s]; }
        __syncthreads();
    }
    const float E1 = r1[0], E2 = r2[0], Pg = r3[0];
    __syncthreads();

    // loss over matched columns (label[j]==c); stash[j] = S[c][j]
    float ls = 0.f;
    const float tmax = (gm2 - gm1) + __logf(E2);             // cancellation-free argmax row
#pragma unroll
    for (int it = 0; it < 4; ++it) {
        const int j = it * 2048 + tid * 4;
        const int4   lv = *(const int4*)(labels + (j & (BS - 1)));
        const float4 sv = *(const float4*)(stash + j);
        if (lv.x == c) ls += (j + 0 == gi1) ? tmax : __logf(E1 - __expf(sv.x - gm1));
        if (lv.y == c) ls += (j + 1 == gi1) ? tmax : __logf(E1 - __expf(sv.y - gm1));
        if (lv.z == c) ls += (j + 2 == gi1) ? tmax : __logf(E1 - __expf(sv.z - gm1));
        if (lv.w == c) ls += (j + 3 == gi1) ? tmax : __logf(E1 - __expf(sv.w - gm1));
    }
    s1[tid] = ls;
    __syncthreads();
    for (int s = 256; s > 0; s >>= 1) {
        if (tid < s) s1[tid] += s1[tid + s];
        __syncthreads();
    }
    if (tid == 0) atomicAdd(out, (s1[0] - Pg) / (float)NROWS);
}

// ================= fused cooperative kernel (single graph node) =================
__global__ __launch_bounds__(512) void k_fused(const float* __restrict__ feats,
                                               const float* __restrict__ protos,
                                               const int* __restrict__ labels,
                                               unsigned short* __restrict__ pB,
                                               float4* __restrict__ PA,
                                               float4* __restrict__ PBd,
                                               float* __restrict__ stash,
                                               float* __restrict__ out) {
    __shared__ char lds[32 * DD * 2];         // 32 KB: gemm stage, then merge scratch
    const int nt = blockIdx.x, tid = threadIdx.x;

    gemm_stage(lds, nt, tid, feats);
    if (nt >= 128 && nt < 142) conv_protos(nt - 128, tid, protos, pB);
    if (nt == 0 && tid == 0) out[0] = 0.f;
    cg::this_grid().sync();                   // pB + out visible everywhere

    gemm_main(lds, nt, tid, pB, labels, PA, PBd, stash);
    cg::this_grid().sync();                   // PA/PBd/stash visible everywhere

    if (nt < NCLS) merge_class(lds, nt, tid, PA, PBd, stash, labels, out);
}

// ================= fallback: same phases as 3 regular kernels =================
__global__ __launch_bounds__(512) void k_prep_fb(const float* __restrict__ protos,
                                                 unsigned short* __restrict__ pB,
                                                 float* __restrict__ out) {
    if (blockIdx.x < 14) conv_protos(blockIdx.x, threadIdx.x, protos, pB);
    else if (threadIdx.x == 0) out[0] = 0.f;
}

__global__ __launch_bounds__(512) void k_gemm_fb(const float* __restrict__ feats,
                                                 const unsigned short* __restrict__ pB,
                                                 const int* __restrict__ labels,
                                                 float4* __restrict__ PA,
                                                 float4* __restrict__ PBd,
                                                 float* __restrict__ stash) {
    __shared__ char lds[32 * DD * 2];
    gemm_stage(lds, blockIdx.x, threadIdx.x, feats);
    gemm_main(lds, blockIdx.x, threadIdx.x, pB, labels, PA, PBd, stash);
}

__global__ __launch_bounds__(512) void k_merge_fb(const float4* __restrict__ PA,
                                                  const float4* __restrict__ PBd,
                                                  const float* __restrict__ stash,
                                                  const int* __restrict__ labels,
                                                  float* __restrict__ out) {
    __shared__ char lds[512 * 4 * 6];
    merge_class(lds, blockIdx.x, threadIdx.x, PA, PBd, stash, labels, out);
}

// ==========================================================================
extern "C" void kernel_launch(void* const* d_in, const int* in_sizes, int n_in,
                              void* d_out, int out_size, void* d_ws, size_t ws_size,
                              hipStream_t stream) {
    const float* feats  = (const float*)d_in[0];
    const int*   labels = (const int*)d_in[1];
    const float* protos = (const float*)d_in[2];
    float* out = (float*)d_out;

    char* w = (char*)d_ws;
    size_t off = 0;
    auto take = [&](size_t n) { size_t o = off; off += (n + 255) & ~(size_t)255; return o; };
    unsigned short* pB    = (unsigned short*)(w + take((size_t)112 * DD * 2));
    float4*         PA    = (float4*)(w + take((size_t)NCLS * NSLAB * 16));
    float4*         PBd   = (float4*)(w + take((size_t)NCLS * NSLAB * 16));
    float*          stash = (float*)(w + take((size_t)NROWS * 4));

    void* args[] = { (void*)&feats, (void*)&protos, (void*)&labels, (void*)&pB,
                     (void*)&PA, (void*)&PBd, (void*)&stash, (void*)&out };
    hipError_t e = hipLaunchCooperativeKernel((const void*)k_fused, dim3(NSLAB), dim3(512),
                                              args, 0, stream);
    if (e != hipSuccess) {                    // deterministic fallback: identical math
        k_prep_fb<<<15, 512, 0, stream>>>(protos, pB, out);
        k_gemm_fb<<<NSLAB, 512, 0, stream>>>(feats, pB, labels, PA, PBd, stash);
        k_merge_fb<<<NCLS, 512, 0, stream>>>(PA, PBd, stash, labels, out);
    }
}